// Round 7
// baseline (260.578 us; speedup 1.0000x reference)
//
#include <hip/hip_runtime.h>

#define BB 4
#define CC 256
#define HH 96
#define WW 128
#define PP 9
#define OFF 4
#define CCH 16           // channels per chunk
#define NPAIR (CCH / 2)  // 8 f16x2 channel pairs per chunk
#define NCH (CC / CCH)   // 16 chunks
#define TPB 288          // 9 dy * 32 pixel-groups
#define TW 72            // staged in2 cols (64 out + 8 halo)
#define XCOLS 64         // output columns per block

typedef _Float16 h2 __attribute__((ext_vector_type(2)));

__device__ __forceinline__ h2 u2h(unsigned u) { union { unsigned u; h2 h; } x; x.u = u; return x.h; }

#if __has_builtin(__builtin_amdgcn_fdot2)
__device__ __forceinline__ float dot2(h2 a, h2 b, float c) { return __builtin_amdgcn_fdot2(a, b, c, false); }
#else
__device__ __forceinline__ float dot2(h2 a, h2 b, float c) { return c + (float)a[0] * (float)b[0] + (float)a[1] * (float)b[1]; }
#endif

__device__ __forceinline__ unsigned pk(float a, float b) {
#if __has_builtin(__builtin_amdgcn_cvt_pkrtz)
  auto r = __builtin_amdgcn_cvt_pkrtz(a, b);
  unsigned u; __builtin_memcpy(&u, &r, 4); return u;
#else
  h2 h; h[0] = (_Float16)a; h[1] = (_Float16)b;
  unsigned u; __builtin_memcpy(&u, &h, 4); return u;
#endif
}

// 768 blocks (4b*96h*2xh) x 288 thr, double-buffered LDS: ONE barrier/chunk.
// Iteration = load(c+1) -> compute(c) -> store(c+1) -> barrier, so prefetch
// register lifetime is intra-iteration (hoistable), not loop-carried.
__global__ __launch_bounds__(TPB, 3) void corr_kernel(const float* __restrict__ in1,
                                                      const float* __restrict__ in2,
                                                      float* __restrict__ out) {
  __shared__ unsigned s2[2][NPAIR][PP][TW];   // 41472 B
  __shared__ unsigned s1[2][NPAIR][XCOLS];    // 4096 B -> 45.5 KB, 3 blocks/CU

  // XCD swizzle: 12-row h-band per XCD so the 9-row dy-halo stays in-XCD L2.
  const int bx = blockIdx.x;
  const int xcd = bx & 7;
  const int slot = bx >> 3;            // 0..95
  const int xh = slot & 1;
  const int s3 = slot >> 1;            // 0..47
  const int b = s3 / 12;
  const int h = xcd * 12 + (s3 % 12);
  const int xbase = xh * XCOLS;

  const int tid = threadIdx.x;
  const int dy = tid >> 5;             // 0..8
  const int pxg = tid & 31;            // 0..31
  const int L0 = pxg << 1;             // 2 output px -> lds cols L0, L0+1

  // staging role: 288 = 8 pairs * 36 col-pairs; edge pairs fully OOB.
  const int sp = tid / 36;             // channel pair 0..7
  const int sc2 = tid - sp * 36;       // col-pair 0..35
  const int sL = sc2 << 1;
  const int sgx = xbase - OFF + sL;    // global x of staged pair (even)
  const bool colv = (sgx >= 0) && (sgx < WW);
  const int sgxc = colv ? sgx : xbase; // clamped: loads always in-bounds
  const int rlo = (h >= OFF) ? 0 : (OFF - h);          // block-uniform
  const int rhi = (PP < HH + OFF - h) ? PP : (HH + OFF - h);

  const int plane = HH * WW;           // 12288
  const long base_b = (long)b * CC * plane;

  // clamped row offsets (block-uniform -> SGPRs); loads are branch-free
  int rowoff[PP];
#pragma unroll
  for (int r = 0; r < PP; ++r) {
    int hr = h + r - OFF;
    hr = hr < 0 ? 0 : (hr >= HH ? HH - 1 : hr);
    rowoff[r] = hr * WW;
  }

  const float* p2a = in2 + base_b + (long)(2 * sp) * plane + sgxc;
  const float* p2b = p2a + plane;
  const int i1p = (tid >> 5) & 7, i1c = tid & 31;  // clamped in1 role
  const bool in1v = (tid < NPAIR * 32);
  const float* p1a = in1 + base_b + (long)(2 * i1p) * plane + h * WW + xbase + (i1c << 1);
  const float* p1b = p1a + plane;

  // pre-zero s2 (both buffers) once: OOB rows/cols never overwritten after.
  for (int i = tid; i < 2 * NPAIR * PP * TW; i += TPB) ((unsigned*)s2)[i] = 0u;

  float acc[2][PP];
#pragma unroll
  for (int px = 0; px < 2; ++px)
#pragma unroll
    for (int dx = 0; dx < PP; ++dx) acc[px][dx] = 0.f;

  float2 fa[PP], fb[PP], ga, gb;

  // ---- chunk 0: load (branch-free), store to buf 0
#pragma unroll
  for (int r = 0; r < PP; ++r) {
    fa[r] = *(const float2*)(p2a + rowoff[r]);
    fb[r] = *(const float2*)(p2b + rowoff[r]);
  }
  ga = *(const float2*)p1a; gb = *(const float2*)p1b;
  __syncthreads();  // pre-zero visible
  if (colv) {
#pragma unroll
    for (int r = 0; r < PP; ++r)
      if (r >= rlo && r < rhi)
        *(uint2*)&s2[0][sp][r][sL] = make_uint2(pk(fa[r].x, fb[r].x), pk(fa[r].y, fb[r].y));
  }
  if (in1v)
    *(uint2*)&s1[0][i1p][i1c << 1] = make_uint2(pk(ga.x, gb.x), pk(ga.y, gb.y));
  __syncthreads();

#pragma unroll 1
  for (int c = 0; c < NCH; ++c) {
    const int buf = c & 1;

    // ---- load chunk c+1 (branch-free, hoistable above compute)
    if (c + 1 < NCH) {
      const long adv = (long)(c + 1) * CCH * plane;
#pragma unroll
      for (int r = 0; r < PP; ++r) {
        fa[r] = *(const float2*)(p2a + adv + rowoff[r]);
        fb[r] = *(const float2*)(p2b + adv + rowoff[r]);
      }
      ga = *(const float2*)(p1a + adv); gb = *(const float2*)(p1b + adv);
    }

    // ---- compute chunk c: 2px x 9dx sliding f16x2 window
#pragma unroll
    for (int p = 0; p < NPAIR; ++p) {
      unsigned q[2], w[10];
      *(uint2*)q = *(const uint2*)&s1[buf][p][L0];
#pragma unroll
      for (int i = 0; i < 5; ++i)
        *(uint2*)&w[2 * i] = *(const uint2*)&s2[buf][p][dy][L0 + 2 * i];
#pragma unroll
      for (int px = 0; px < 2; ++px)
#pragma unroll
        for (int dx = 0; dx < PP; ++dx)
          acc[px][dx] = dot2(u2h(w[px + dx]), u2h(q[px]), acc[px][dx]);
    }

    // ---- store chunk c+1 into the other buffer (no barrier needed before:
    // buf^1 readers finished before the barrier that ended iter c-1)
    if (c + 1 < NCH) {
      if (colv) {
#pragma unroll
        for (int r = 0; r < PP; ++r)
          if (r >= rlo && r < rhi)
            *(uint2*)&s2[buf ^ 1][sp][r][sL] = make_uint2(pk(fa[r].x, fb[r].x), pk(fa[r].y, fb[r].y));
      }
      if (in1v)
        *(uint2*)&s1[buf ^ 1][i1p][i1c << 1] = make_uint2(pk(ga.x, gb.x), pk(ga.y, gb.y));
    }
    __syncthreads();  // single barrier per chunk
  }

  // ---- epilogue: 9 coalesced float2 stores
  const int gx0 = xbase + L0;
  float* ob = out + ((long)(b * PP + dy) * PP) * plane + h * WW + gx0;
#pragma unroll
  for (int dx = 0; dx < PP; ++dx)
    *(float2*)(ob + (long)dx * plane) = make_float2(acc[0][dx], acc[1][dx]);
}

extern "C" void kernel_launch(void* const* d_in, const int* in_sizes, int n_in,
                              void* d_out, int out_size, void* d_ws, size_t ws_size,
                              hipStream_t stream) {
  const float* in1 = (const float*)d_in[0];
  const float* in2 = (const float*)d_in[1];
  float* out = (float*)d_out;
  // 768 blocks = 4b * 96h * 2xh (xcd-swizzled), 288 thr = 9dy * 32pxg
  corr_kernel<<<dim3(BB * HH * 2), dim3(TPB), 0, stream>>>(in1, in2, out);
}

// Round 8
// 225.842 us; speedup vs baseline: 1.1538x; 1.1538x over previous
//
#include <hip/hip_runtime.h>

#define BB 4
#define CC 256
#define HH 96
#define WW 128
#define PP 9
#define OFF 4
#define CCH 16           // channels per chunk
#define NPAIR (CCH / 2)  // 8 f16x2 channel pairs per chunk
#define NCH (CC / CCH)   // 16 chunks
#define TPB 288          // 9 dy * 32 pixel-groups (4 px each -> full 128 cols)
#define TW 144           // s2 row: 136 used (4 pad + 128 + 4 pad) + 8 spare, /4 aligned

typedef _Float16 h2 __attribute__((ext_vector_type(2)));

__device__ __forceinline__ h2 u2h(unsigned u) { union { unsigned u; h2 h; } x; x.u = u; return x.h; }

#if __has_builtin(__builtin_amdgcn_fdot2)
__device__ __forceinline__ float dot2(h2 a, h2 b, float c) { return __builtin_amdgcn_fdot2(a, b, c, false); }
#else
__device__ __forceinline__ float dot2(h2 a, h2 b, float c) { return c + (float)a[0] * (float)b[0] + (float)a[1] * (float)b[1]; }
#endif

__device__ __forceinline__ unsigned pk(float a, float b) {
#if __has_builtin(__builtin_amdgcn_cvt_pkrtz)
  auto r = __builtin_amdgcn_cvt_pkrtz(a, b);
  unsigned u; __builtin_memcpy(&u, &r, 4); return u;
#else
  h2 h; h[0] = (_Float16)a; h[1] = (_Float16)b;
  unsigned u; __builtin_memcpy(&u, &h, 4); return u;
#endif
}

// 384 blocks (4b*96h), 288 thr = 9dy*32pxg, 4 px/thread (full 128-col rows).
// All LDS traffic is b128: compute reads 4x b128 per pair (1.78 B/dot2 vs
// R5's 2.67), staging stores 1x b128 per (pair,row). R5's proven 2-barrier
// single-buffer pipeline kept (R6/R7 double-buffer variants both regressed).
__global__ __launch_bounds__(TPB, 2) void corr_kernel(const float* __restrict__ in1,
                                                      const float* __restrict__ in2,
                                                      float* __restrict__ out) {
  __shared__ unsigned s2[NPAIR][PP][TW];   // 41472 B
  __shared__ unsigned s1[NPAIR][WW];       // 4096 B -> 45.5 KB

  // XCD swizzle: 12-row h-band per XCD so the 9-row dy-halo stays in-XCD L2.
  const int bx = blockIdx.x;
  const int xcd = bx & 7;
  const int slot = bx >> 3;            // 0..47
  const int b = slot / 12;
  const int h = xcd * 12 + (slot % 12);

  const int tid = threadIdx.x;
  const int dy = tid >> 5;             // 0..8
  const int pxg = tid & 31;            // 0..31
  const int L0 = pxg << 2;             // 4 output px -> lds cols L0..L0+3 (16B aligned)

  // in2 staging role: fixed (pair, col-quad), rows 0..8. 288 = 8 pairs * 36 quads.
  // Quad sq covers lds cols 4sq..4sq+3 = global x 4sq-4..4sq-1.
  // sq in [1,32] <-> x in [0,127]: valid. sq 0/33 are zero-pads (never stored,
  // pre-zeroed); sq 34/35 never read.
  const int sp = tid / 36;             // channel pair 0..7
  const int sq = tid - sp * 36;        // col-quad 0..35
  const bool qv = (sq >= 1) && (sq <= 32);
  const int x0s = (sq << 2) - OFF;     // global x of quad start (0..124 when valid)
  const int rlo = (h >= OFF) ? 0 : (OFF - h);            // block-uniform
  const int rhi = (PP < HH + OFF - h) ? PP : (HH + OFF - h);

  const int plane = HH * WW;           // 12288
  const long base_b = (long)b * CC * plane;

  const float* p2a = in2 + base_b + (long)(2 * sp) * plane + (long)(h - OFF) * WW + x0s;
  const float* p2b = p2a + plane;
  const int i1p = (tid >> 5) & 7, i1q = tid & 31;  // in1 role (tid<256)
  const bool in1v = (tid < NPAIR * 32);
  const float* p1a = in1 + base_b + (long)(2 * i1p) * plane + h * WW + (i1q << 2);
  const float* p1b = p1a + plane;

  // pre-zero s2 once (pads + OOB rows never overwritten afterwards)
  for (int i = tid; i < NPAIR * PP * (TW / 4); i += TPB)
    *(((uint4*)s2) + i) = make_uint4(0u, 0u, 0u, 0u);

  float acc[4][PP];
#pragma unroll
  for (int px = 0; px < 4; ++px)
#pragma unroll
    for (int dx = 0; dx < PP; ++dx) acc[px][dx] = 0.f;

  float4 fa[PP], fb[PP], ga, gb;

  // ---- prefetch chunk 0
  if (qv) {
#pragma unroll
    for (int r = 0; r < PP; ++r)
      if (r >= rlo && r < rhi) {
        fa[r] = *(const float4*)(p2a + r * WW);
        fb[r] = *(const float4*)(p2b + r * WW);
      }
  }
  if (in1v) { ga = *(const float4*)p1a; gb = *(const float4*)p1b; }
  __syncthreads();  // pre-zero visible

#pragma unroll 1
  for (int c = 0; c < NCH; ++c) {
    // ---- store phase: pk prefetched regs -> LDS (all b128)
    if (qv) {
#pragma unroll
      for (int r = 0; r < PP; ++r)
        if (r >= rlo && r < rhi)
          *(uint4*)&s2[sp][r][sq << 2] =
              make_uint4(pk(fa[r].x, fb[r].x), pk(fa[r].y, fb[r].y),
                         pk(fa[r].z, fb[r].z), pk(fa[r].w, fb[r].w));
    }
    if (in1v)
      *(uint4*)&s1[i1p][i1q << 2] =
          make_uint4(pk(ga.x, gb.x), pk(ga.y, gb.y), pk(ga.z, gb.z), pk(ga.w, gb.w));
    __syncthreads();  // A: LDS visible

    // ---- prefetch chunk c+1 (in flight during compute)
    if (c + 1 < NCH) {
      const long adv = (long)(c + 1) * CCH * plane;
      if (qv) {
#pragma unroll
        for (int r = 0; r < PP; ++r)
          if (r >= rlo && r < rhi) {
            fa[r] = *(const float4*)(p2a + adv + r * WW);
            fb[r] = *(const float4*)(p2b + adv + r * WW);
          }
      }
      if (in1v) { ga = *(const float4*)(p1a + adv); gb = *(const float4*)(p1b + adv); }
    }

    // ---- compute chunk c: 4px x 9dx sliding window, all b128 reads
#pragma unroll
    for (int p = 0; p < NPAIR; ++p) {
      unsigned q[4], w[12];
      *(uint4*)q = *(const uint4*)&s1[p][L0];
      *(uint4*)&w[0] = *(const uint4*)&s2[p][dy][L0];
      *(uint4*)&w[4] = *(const uint4*)&s2[p][dy][L0 + 4];
      *(uint4*)&w[8] = *(const uint4*)&s2[p][dy][L0 + 8];
#pragma unroll
      for (int px = 0; px < 4; ++px)
#pragma unroll
        for (int dx = 0; dx < PP; ++dx)
          acc[px][dx] = dot2(u2h(w[px + dx]), u2h(q[px]), acc[px][dx]);
    }
    __syncthreads();  // B: reads done before next store phase
  }

  // ---- epilogue: 9 coalesced float4 stores
  float* ob = out + ((long)(b * PP + dy) * PP) * plane + h * WW + L0;
#pragma unroll
  for (int dx = 0; dx < PP; ++dx)
    *(float4*)(ob + (long)dx * plane) = make_float4(acc[0][dx], acc[1][dx], acc[2][dx], acc[3][dx]);
}

extern "C" void kernel_launch(void* const* d_in, const int* in_sizes, int n_in,
                              void* d_out, int out_size, void* d_ws, size_t ws_size,
                              hipStream_t stream) {
  const float* in1 = (const float*)d_in[0];
  const float* in2 = (const float*)d_in[1];
  float* out = (float*)d_out;
  // 384 blocks = 4b * 96h (xcd-swizzled), 288 thr = 9dy * 32pxg * 4px
  corr_kernel<<<dim3(BB * HH), dim3(TPB), 0, stream>>>(in1, in2, out);
}